// Round 11
// baseline (228.345 us; speedup 1.0000x reference)
//
#include <hip/hip_runtime.h>
#include <hip/hip_bf16.h>

#define HID 64
#define HEADS 4

typedef short s16x8 __attribute__((ext_vector_type(8)));   // 8 bf16/f16 (4 VGPRs)
typedef short s16x4 __attribute__((ext_vector_type(4)));
typedef float f32x4 __attribute__((ext_vector_type(4)));
typedef float f32x2 __attribute__((ext_vector_type(2)));

// flag convention: *flag >= 8  =>  float inputs are fp32; else bf16.
__device__ __forceinline__ float ldw(const void* p, long i, bool f32) {
    return f32 ? ((const float*)p)[i] : (float)((const __hip_bfloat16*)p)[i];
}

__device__ __forceinline__ unsigned short f2b(float f) {   // fp32 -> bf16 bits (RNE, finite)
    unsigned int u = __builtin_bit_cast(unsigned int, f);
    u += 0x7FFF + ((u >> 16) & 1);
    return (unsigned short)(u >> 16);
}
__device__ __forceinline__ float b2f(unsigned short s) {
    unsigned int u = ((unsigned int)s) << 16;
    return __builtin_bit_cast(float, u);
}
__device__ __forceinline__ short f2h(float f) {            // fp32 -> fp16 bits
    return __builtin_bit_cast(short, (_Float16)f);
}

#if __has_builtin(__builtin_amdgcn_exp2f)
#define EXP2(x) __builtin_amdgcn_exp2f(x)     // single v_exp_f32
#else
#define EXP2(x) exp2f(x)
#endif
#if __has_builtin(__builtin_amdgcn_rcpf)
#define RCP(x) __builtin_amdgcn_rcpf(x)
#else
#define RCP(x) (1.0f / (x))
#endif

// ---------------- shared edge-softmax core: depth-16 raw-load pipeline (R25) -----
// sv holds UNSCALED u16 sender ids; index = readlane(sv,j)*HID (scalar shift).
// lanes with lane >= cR must arrive with sv == 0 (safe gather of h row 0).
// Two 8-deep banks q/p: all 16 loads in flight at wave start for deg<=16.
__device__ __forceinline__ void edge_softmax(
    const _Float16* __restrict__ hbp, int sv, int cR,
    const f32x2 (&w0p)[2], const f32x2 (&cp)[2],
    f32x2 (&lp)[2], f32x2 (&ap)[2]) {
    #define LD(j) hbp[(long)(__builtin_amdgcn_readlane(sv, (j)) * HID)]
    #define STEP(hc) {                                                     \
        float _h = (float)(hc);              /* cvt at USE time */         \
        _Pragma("unroll")                                                  \
        for (int q = 0; q < 2; q++) {                                      \
            f32x2 t = w0p[q] * _h + cp[q];                                 \
            f32x2 u = t * 0.2f;                                            \
            t.x = fmaxf(t.x, u.x); t.y = fmaxf(t.y, u.y);                  \
            f32x2 pe; pe.x = EXP2(t.x); pe.y = EXP2(t.y);                  \
            lp[q] += pe;                                                   \
            ap[q] += pe * _h;                                              \
        } }

    _Float16 q0 = LD(0), q1 = LD(1), q2 = LD(2), q3 = LD(3);   // bank q: [j, j+8)
    _Float16 q4 = LD(4), q5 = LD(5), q6 = LD(6), q7 = LD(7);
    _Float16 p0 = LD(8), p1 = LD(9), p2 = LD(10), p3 = LD(11); // bank p: [j+8, j+16)
    _Float16 p4 = LD(12), p5 = LD(13), p6 = LD(14), p7 = LD(15);
    int j = 0;
    for (; j + 8 <= cR; j += 8) {
        _Float16 a0 = q0, a1 = q1, a2 = q2, a3 = q3;
        _Float16 a4 = q4, a5 = q5, a6 = q6, a7 = q7;
        q0 = p0; q1 = p1; q2 = p2; q3 = p3;          // shift p -> q
        q4 = p4; q5 = p5; q6 = p6; q7 = p7;
        if (j + 16 < cR) {                           // refill p 16 ahead (guarded)
            p0 = LD(j + 16); p1 = LD(j + 17); p2 = LD(j + 18); p3 = LD(j + 19);
            p4 = LD(j + 20); p5 = LD(j + 21); p6 = LD(j + 22); p7 = LD(j + 23);
        }
        STEP(a0); STEP(a1); STEP(a2); STEP(a3);
        STEP(a4); STEP(a5); STEP(a6); STEP(a7);
    }
    int remn = cR - j;                       // 0..7 tail, bank q already loaded
    if (remn > 0) STEP(q0);
    if (remn > 1) STEP(q1);
    if (remn > 2) STEP(q2);
    if (remn > 3) STEP(q3);
    if (remn > 4) STEP(q4);
    if (remn > 5) STEP(q5);
    if (remn > 6) STEP(q6);
    #undef LD
    #undef STEP
}

// ---------------- prep: SELF-DETECT + W^T + folded attn consts + cnt zero -------
__global__ __launch_bounds__(256) void prep_kernel(
    const void* __restrict__ nodes,
    const void* __restrict__ W0, const void* __restrict__ W1, const void* __restrict__ W2,
    const void* __restrict__ Wl0, const void* __restrict__ bl0,
    const void* __restrict__ Wl1, const void* __restrict__ bl1,
    const void* __restrict__ Wl2, const void* __restrict__ bl2,
    int* __restrict__ flag_out,
    unsigned short* __restrict__ T0, unsigned short* __restrict__ T1,
    unsigned short* __restrict__ T2, float* __restrict__ Wlp,
    int* __restrict__ cnt, int N64) {
    __shared__ int sflag;
    if (threadIdx.x == 0) sflag = 0;
    __syncthreads();
    {
        const uint4* pw = (const uint4*)nodes;       // 2048 uint4 = 16384 ushorts
        int hits = 0;
        for (int i = threadIdx.x; i < 2048; i += 256) {
            uint4 u = pw[i];
            unsigned int w[4] = {u.x, u.y, u.z, u.w};
            #pragma unroll
            for (int j = 0; j < 4; j++) {
                if ((w[j] & 0x7F80u) == 0x7F80u) hits++;               // low half
                if (((w[j] >> 16) & 0x7F80u) == 0x7F80u) hits++;       // high half
            }
        }
        if (__ballot(hits != 0)) { if ((threadIdx.x & 63) == 0) sflag = 1; }
    }
    __syncthreads();
    const bool f32 = (sflag != 0);
    if (blockIdx.x == 0 && threadIdx.x == 0) *flag_out = f32 ? 100 : 0;

    int g = blockIdx.x * 256 + threadIdx.x;
    int stride = gridDim.x * 256;

    for (int i = g; i < N64; i += stride) cnt[i] = 0;    // full padded range

    // W [K,64] -> W^T [64,K]  (output-indexed: writes coalesce)
    for (int o = g; o < 40960; o += stride) {
        if (o < 8192) {                                  // T0: [64][128] from W0 [128][64]
            int n = o >> 7, k = o & 127;
            T0[o] = f32 ? f2b(((const float*)W0)[k * 64 + n])
                        : ((const unsigned short*)W0)[k * 64 + n];    // raw bf16 copy
        } else {
            int oo = o - 8192;
            const void* W; unsigned short* T;
            if (oo < 16384) { W = W1; T = T1; }
            else            { W = W2; T = T2; oo -= 16384; }
            int n = oo >> 8, k = oo & 255;               // T: [64][256]
            float w = ldw(W, k * 64 + n, f32);
            T[oo] = (unsigned short)f2h(w);              // fp16 both worlds
        }
    }
    // folded attention consts: per layer L, 16 floats
    if (blockIdx.x == 0 && threadIdx.x < 48) {
        int L = threadIdx.x >> 4, s = threadIdx.x & 15;
        const void* W = (L == 0) ? Wl0 : ((L == 1) ? Wl1 : Wl2);
        const void* B = (L == 0) ? bl0 : ((L == 1) ? bl1 : bl2);
        float v = 0.f;
        if (s < 8)       v = ldw(W, s, f32);
        else if (s < 12) v = ldw(B, s - 8, f32);
        Wlp[L * 16 + s] = v * 1.44269504f;
    }
}

// ---------------- MFMA GEMM body: h = A @ W + b ----------------
template <int K, int AMODE>
__device__ __forceinline__ void gemm_body(const unsigned short* __restrict__ Ah,
                                          const unsigned short* __restrict__ Wt,
                                          const void* __restrict__ bq,
                                          bool f32,
                                          _Float16* __restrict__ h, int M, int blockId) {
    constexpr int KP = K + 8;
    __shared__ __align__(16) unsigned short Ws[64 * KP];
    int tid = threadIdx.x;
    #pragma unroll
    for (int it = 0; it < (64 * K) / 2048; it++) {       // coalesced 16B staging
        int i = it * 2048 + tid * 8;
        int row = i / K, col = i % K;
        *(s16x8*)&Ws[row * KP + col] = *(const s16x8*)(Wt + i);
    }
    __syncthreads();

    int lane = tid & 63, wv = tid >> 6;
    int m16 = lane & 15, quad = lane >> 4;

    int tiles = (M + 15) >> 4;
    int tile = blockId * 4 + wv;
    if (tile >= tiles) return;

    float bias[4];
    #pragma unroll
    for (int t = 0; t < 4; t++) bias[t] = ldw(bq, 16 * t + m16, f32);

    int m0 = tile << 4;
    int row = m0 + m16;
    bool rv = row < M;
    long abase = (long)row * K;
    f32x4 acc[4] = {{0.f,0.f,0.f,0.f},{0.f,0.f,0.f,0.f},{0.f,0.f,0.f,0.f},{0.f,0.f,0.f,0.f}};

    #pragma unroll
    for (int ks = 0; ks < K / 32; ks++) {
        int kb = ks * 32 + quad * 8;
        s16x8 b[4];
        #pragma unroll
        for (int t = 0; t < 4; t++)
            b[t] = *(const s16x8*)&Ws[(16 * t + m16) * KP + kb];     // LDS, 2-way max
        if (AMODE == 3) {
            const float* Af = (const float*)Ah;
            f32x4 v0 = {0.f,0.f,0.f,0.f}, v1 = {0.f,0.f,0.f,0.f};
            if (rv) {
                v0 = *(const f32x4*)(Af + abase + kb);
                v1 = *(const f32x4*)(Af + abase + kb + 4);
            }
            s16x8 ah, al;
            #pragma unroll
            for (int jj = 0; jj < 8; jj++) {
                float f = (jj < 4) ? v0[jj] : v1[jj - 4];
                unsigned short hb = f2b(f);
                ah[jj] = (short)hb;
                al[jj] = (short)f2b(f - b2f(hb));
            }
            #pragma unroll
            for (int t = 0; t < 4; t++)
                acc[t] = __builtin_amdgcn_mfma_f32_16x16x32_bf16(ah, b[t], acc[t], 0, 0, 0);
            #pragma unroll
            for (int t = 0; t < 4; t++)
                acc[t] = __builtin_amdgcn_mfma_f32_16x16x32_bf16(al, b[t], acc[t], 0, 0, 0);
        } else {
            s16x8 ah = rv ? *(const s16x8*)(Ah + abase + kb) : (s16x8){0,0,0,0,0,0,0,0};
            if (AMODE == 0) {
                #pragma unroll
                for (int t = 0; t < 4; t++)
                    acc[t] = __builtin_amdgcn_mfma_f32_16x16x32_bf16(ah, b[t], acc[t], 0, 0, 0);
            } else {
                #pragma unroll
                for (int t = 0; t < 4; t++)
                    acc[t] = __builtin_amdgcn_mfma_f32_16x16x32_f16(ah, b[t], acc[t], 0, 0, 0);
            }
        }
    }

    #pragma unroll
    for (int t = 0; t < 4; t++) {
        #pragma unroll
        for (int r = 0; r < 4; r++) {
            int orow = m0 + quad * 4 + r;        // C/D: col=lane&15, row=quad*4+reg
            if (orow < M) h[(long)orow * 64 + 16 * t + m16] = (_Float16)(acc[t][r] + bias[t]);
        }
    }
}

// layers 1-2: A = x fp16 single plane, BOTH worlds. flag only picks bias dtype.
template <int K>
__global__ __launch_bounds__(256) void gemm_mfma(const unsigned short* __restrict__ Ah,
                                                 const unsigned short* __restrict__ Wt,
                                                 const void* __restrict__ bq,
                                                 const int* __restrict__ flag,
                                                 _Float16* __restrict__ h, int M) {
    const bool f32 = (*flag >= 8);
    gemm_body<K, 1>(Ah, Wt, bq, f32, h, M, blockIdx.x);
}

// ---------------- fused: slot scatter + layer-0 GEMM (single atomic pass) --------
__global__ __launch_bounds__(256) void gemm0_scatter(
    const void* __restrict__ nodes,
    const unsigned short* __restrict__ Wt, const void* __restrict__ bq,
    const int* __restrict__ flag, _Float16* __restrict__ h, int M,
    const int* __restrict__ recv, const int* __restrict__ send,
    int* __restrict__ cnt, unsigned short* __restrict__ slots, int E, int scatBlocks) {
    if ((int)blockIdx.x < scatBlocks) {
        int g = blockIdx.x * 256 + threadIdx.x;
        int stride = scatBlocks * 256;
        for (int i = g; i < E; i += stride) {
            int r = recv[i];
            int pos = atomicAdd(&cnt[r], 1);
            if (pos < 64) slots[r * 64 + pos] = (unsigned short)send[i];
        }
    } else {
        const bool f32 = (*flag >= 8);
        int blockId = blockIdx.x - scatBlocks;
        if (f32) gemm_body<128, 3>((const unsigned short*)nodes, Wt, bq,
                                   true, h, M, blockId);
        else     gemm_body<128, 0>((const unsigned short*)nodes, Wt, bq,
                                   false, h, M, blockId);
    }
}

// ---------------- Attention: segment softmax (no-max, exp2-folded) + aggregate ----
// R26 DIAGNOSTIC: runtime `reps` arg -- layer-0 runs its body twice (idempotent:
// reads h/cnt/slots/wlp only, writes xh deterministically). Pushes the dispatch
// to ~70us so it outranks the 44us harness fills in rocprof top-5, exposing
// VGPR_Count / VALUBusy / Occupancy / FETCH for the attn kernel for the first
// time. Otherwise byte-identical to R10 (best = 207.8us, banked).
__global__ __launch_bounds__(256) void attn_kernel(
    const _Float16* __restrict__ h, const int* __restrict__ cnt,
    const unsigned short* __restrict__ slots,
    const float* __restrict__ wlp,          // 12 pre-folded consts (prep_kernel)
    const int* __restrict__ flag,
    unsigned short* __restrict__ xh,
    void* __restrict__ out, int n, int last, int reps) {
    const bool f32 = (*flag >= 8);
    int lane = threadIdx.x & 63;
    int r = __builtin_amdgcn_readfirstlane(blockIdx.x * 4 + (threadIdx.x >> 6));
    if (r >= n) return;

    int cR = cnt[r];
    cR = min(cR, 64);
    int sv = slots[r * 64 + lane];           // one coalesced 128B row per wave
    if (lane >= cR) sv = 0;                  // clamp: valid h row, value unused

    float hr = (float)h[(long)r * HID + lane];
    f32x4 w0v = *(const f32x4*)(wlp);        // already *log2e
    f32x4 w1v = *(const f32x4*)(wlp + 4);
    f32x4 bv  = *(const f32x4*)(wlp + 8);
    f32x2 w0p[2], cp[2];
    #pragma unroll
    for (int q = 0; q < 2; q++) {
        #pragma unroll
        for (int c = 0; c < 2; c++) {
            int k = 2 * q + c;
            w0p[q][c] = w0v[k];
            cp[q][c] = fmaf(hr, w1v[k], bv[k]);  // receiver part: loop-invariant
        }
    }

    for (int rep = 0; rep < reps; rep++) {   // reps=1 normally; 2 = diagnostic
        f32x2 lp[2] = {{0.f, 0.f}, {0.f, 0.f}};
        f32x2 ap[2] = {{0.f, 0.f}, {0.f, 0.f}};
        edge_softmax(h + lane, sv, cR, w0p, cp, lp, ap);

        bool has = (cR > 0);
        if (!last) {
            float v[4];
            #pragma unroll
            for (int k = 0; k < HEADS; k++) {
                float a = has ? ap[k >> 1][k & 1] * RCP(lp[k >> 1][k & 1]) : 0.f;
                v[k] = (a > 0.f) ? a : (__expf(a) - 1.f);    // elu
            }
            long o = (long)r * (HID * HEADS) + lane * HEADS; // reshape: d*HEADS+k
            s16x4 vf;                                        // single fp16 plane
            #pragma unroll
            for (int k = 0; k < HEADS; k++) vf[k] = f2h(v[k]);
            *(s16x4*)(xh + o) = vf;
        } else {
            float s = 0.f;
            #pragma unroll
            for (int k = 0; k < HEADS; k++)
                s += has ? ap[k >> 1][k & 1] * RCP(lp[k >> 1][k & 1]) : 0.f;
            float a = s * 0.25f;                             // mean over heads
            a = (a > 0.f) ? a : (__expf(a) - 1.f);           // elu
            if (f32) ((float*)out)[(long)r * HID + lane] = a;
            else     ((__hip_bfloat16*)out)[(long)r * HID + lane] = (__hip_bfloat16)a;
        }
    }
}

// ---------------- launch ----------------

extern "C" void kernel_launch(void* const* d_in, const int* in_sizes, int n_in,
                              void* d_out, int out_size, void* d_ws, size_t ws_size,
                              hipStream_t stream) {
    const void* nodes    = d_in[0];
    const int* senders   = (const int*)d_in[1];
    const int* receivers = (const int*)d_in[2];
    const void* Wq0 = d_in[3];  const void* bq0 = d_in[4];
    const void* Wl0 = d_in[5];  const void* bl0 = d_in[6];
    const void* Wq1 = d_in[7];  const void* bq1 = d_in[8];
    const void* Wl1 = d_in[9];  const void* bl1 = d_in[10];
    const void* Wq2 = d_in[11]; const void* bq2 = d_in[12];
    const void* Wl2 = d_in[13]; const void* bl2 = d_in[14];

    int N = in_sizes[0] / 128;
    int E = in_sizes[1];
    int N64 = ((N + 63) / 64) * 64;

    char* p = (char*)d_ws;
    int* flag = (int*)p;            p += 64;
    _Float16* h = (_Float16*)p;     p += (size_t)N64 * 64 * 2;          // 3.2 MB (L2-fit)
    unsigned short* xh = (unsigned short*)p;  p += (size_t)N64 * 256 * 2; // 12.8 MB fp16
    unsigned short* Wt0 = (unsigned short*)p; p += 128 * 64 * 2;
    unsigned short* Wt1 = (unsigned short*)p; p += 256 * 64 * 2;
    unsigned short* Wt2 = (unsigned short*)p; p += 256 * 64 * 2;
    float* Wlp = (float*)p;         p += 64 * 4;                        // 3x16 floats
    int* cnt = (int*)p;             p += (size_t)N64 * 4;
    unsigned short* slots = (unsigned short*)p; p += (size_t)N64 * 64 * 2; // 3.2 MB u16

    prep_kernel<<<64, 256, 0, stream>>>(nodes, Wq0, Wq1, Wq2,
                                        Wl0, bl0, Wl1, bl1, Wl2, bl2,
                                        flag, Wt0, Wt1, Wt2, Wlp, cnt, N64);

    int attnGrid = (N + 3) / 4;
    int tiles = (N + 15) / 16;
    int gemmGrid = (tiles + 3) / 4;
    int scatBlocks = gemmGrid;

    // layer-0 GEMM (direct nodes read, in-register hi/lo for f32) + slot scatter
    gemm0_scatter<<<scatBlocks + gemmGrid, 256, 0, stream>>>(nodes, Wt0, bq0, flag, h, N,
                                                             receivers, senders, cnt, slots,
                                                             E, scatBlocks);
    // DIAGNOSTIC round: attn0 runs body 2x (idempotent) to surface its counters
    attn_kernel<<<attnGrid, 256, 0, stream>>>(h, cnt, slots, Wlp + 0, flag,
                                              xh, nullptr, N, 0, 2);
    // layer 1
    gemm_mfma<256><<<gemmGrid, 256, 0, stream>>>(xh, Wt1, bq1, flag, h, N);
    attn_kernel<<<attnGrid, 256, 0, stream>>>(h, cnt, slots, Wlp + 16, flag,
                                              xh, nullptr, N, 0, 1);
    // layer 2 (last: mean over heads + elu)
    gemm_mfma<256><<<gemmGrid, 256, 0, stream>>>(xh, Wt2, bq2, flag, h, N);
    attn_kernel<<<attnGrid, 256, 0, stream>>>(h, cnt, slots, Wlp + 32, flag,
                                              nullptr, d_out, N, 1, 1);
}

// Round 13
// 208.419 us; speedup vs baseline: 1.0956x; 1.0956x over previous
//
#include <hip/hip_runtime.h>
#include <hip/hip_bf16.h>

#define HID 64
#define HEADS 4

typedef short s16x8 __attribute__((ext_vector_type(8)));   // 8 bf16/f16 (4 VGPRs)
typedef short s16x4 __attribute__((ext_vector_type(4)));
typedef float f32x4 __attribute__((ext_vector_type(4)));
typedef float f32x2 __attribute__((ext_vector_type(2)));

// flag convention: *flag >= 8  =>  float inputs are fp32; else bf16.
__device__ __forceinline__ float ldw(const void* p, long i, bool f32) {
    return f32 ? ((const float*)p)[i] : (float)((const __hip_bfloat16*)p)[i];
}

__device__ __forceinline__ unsigned short f2b(float f) {   // fp32 -> bf16 bits (RNE, finite)
    unsigned int u = __builtin_bit_cast(unsigned int, f);
    u += 0x7FFF + ((u >> 16) & 1);
    return (unsigned short)(u >> 16);
}
__device__ __forceinline__ float b2f(unsigned short s) {
    unsigned int u = ((unsigned int)s) << 16;
    return __builtin_bit_cast(float, u);
}
__device__ __forceinline__ short f2h(float f) {            // fp32 -> fp16 bits
    return __builtin_bit_cast(short, (_Float16)f);
}

#if __has_builtin(__builtin_amdgcn_exp2f)
#define EXP2(x) __builtin_amdgcn_exp2f(x)     // single v_exp_f32
#else
#define EXP2(x) exp2f(x)
#endif
#if __has_builtin(__builtin_amdgcn_rcpf)
#define RCP(x) __builtin_amdgcn_rcpf(x)
#else
#define RCP(x) (1.0f / (x))
#endif

// ---------------- shared edge-softmax core: depth-16 raw-load pipeline (R25) -----
// sv holds UNSCALED u16 sender ids; index = readlane(sv,j)*HID (scalar shift).
// lanes with lane >= cR must arrive with sv == 0 (safe gather of h row 0).
// Two 8-deep banks q/p: all 16 loads in flight at wave start for deg<=16.
__device__ __forceinline__ void edge_softmax(
    const _Float16* __restrict__ hbp, int sv, int cR,
    const f32x2 (&w0p)[2], const f32x2 (&cp)[2],
    f32x2 (&lp)[2], f32x2 (&ap)[2]) {
    #define LD(j) hbp[(long)(__builtin_amdgcn_readlane(sv, (j)) * HID)]
    #define STEP(hc) {                                                     \
        float _h = (float)(hc);              /* cvt at USE time */         \
        _Pragma("unroll")                                                  \
        for (int q = 0; q < 2; q++) {                                      \
            f32x2 t = w0p[q] * _h + cp[q];                                 \
            f32x2 u = t * 0.2f;                                            \
            t.x = fmaxf(t.x, u.x); t.y = fmaxf(t.y, u.y);                  \
            f32x2 pe; pe.x = EXP2(t.x); pe.y = EXP2(t.y);                  \
            lp[q] += pe;                                                   \
            ap[q] += pe * _h;                                              \
        } }

    _Float16 q0 = LD(0), q1 = LD(1), q2 = LD(2), q3 = LD(3);   // bank q: [j, j+8)
    _Float16 q4 = LD(4), q5 = LD(5), q6 = LD(6), q7 = LD(7);
    _Float16 p0 = LD(8), p1 = LD(9), p2 = LD(10), p3 = LD(11); // bank p: [j+8, j+16)
    _Float16 p4 = LD(12), p5 = LD(13), p6 = LD(14), p7 = LD(15);
    int j = 0;
    for (; j + 8 <= cR; j += 8) {
        _Float16 a0 = q0, a1 = q1, a2 = q2, a3 = q3;
        _Float16 a4 = q4, a5 = q5, a6 = q6, a7 = q7;
        q0 = p0; q1 = p1; q2 = p2; q3 = p3;          // shift p -> q
        q4 = p4; q5 = p5; q6 = p6; q7 = p7;
        if (j + 16 < cR) {                           // refill p 16 ahead (guarded)
            p0 = LD(j + 16); p1 = LD(j + 17); p2 = LD(j + 18); p3 = LD(j + 19);
            p4 = LD(j + 20); p5 = LD(j + 21); p6 = LD(j + 22); p7 = LD(j + 23);
        }
        STEP(a0); STEP(a1); STEP(a2); STEP(a3);
        STEP(a4); STEP(a5); STEP(a6); STEP(a7);
    }
    int remn = cR - j;                       // 0..7 tail, bank q already loaded
    if (remn > 0) STEP(q0);
    if (remn > 1) STEP(q1);
    if (remn > 2) STEP(q2);
    if (remn > 3) STEP(q3);
    if (remn > 4) STEP(q4);
    if (remn > 5) STEP(q5);
    if (remn > 6) STEP(q6);
    #undef LD
    #undef STEP
}

// ---------------- prep: SELF-DETECT + W^T + folded attn consts + cnt zero -------
__global__ __launch_bounds__(256) void prep_kernel(
    const void* __restrict__ nodes,
    const void* __restrict__ W0, const void* __restrict__ W1, const void* __restrict__ W2,
    const void* __restrict__ Wl0, const void* __restrict__ bl0,
    const void* __restrict__ Wl1, const void* __restrict__ bl1,
    const void* __restrict__ Wl2, const void* __restrict__ bl2,
    int* __restrict__ flag_out,
    unsigned short* __restrict__ T0, unsigned short* __restrict__ T1,
    unsigned short* __restrict__ T2, float* __restrict__ Wlp,
    int* __restrict__ cnt, int N64) {
    __shared__ int sflag;
    if (threadIdx.x == 0) sflag = 0;
    __syncthreads();
    {
        const uint4* pw = (const uint4*)nodes;       // 2048 uint4 = 16384 ushorts
        int hits = 0;
        for (int i = threadIdx.x; i < 2048; i += 256) {
            uint4 u = pw[i];
            unsigned int w[4] = {u.x, u.y, u.z, u.w};
            #pragma unroll
            for (int j = 0; j < 4; j++) {
                if ((w[j] & 0x7F80u) == 0x7F80u) hits++;               // low half
                if (((w[j] >> 16) & 0x7F80u) == 0x7F80u) hits++;       // high half
            }
        }
        if (__ballot(hits != 0)) { if ((threadIdx.x & 63) == 0) sflag = 1; }
    }
    __syncthreads();
    const bool f32 = (sflag != 0);
    if (blockIdx.x == 0 && threadIdx.x == 0) *flag_out = f32 ? 100 : 0;

    int g = blockIdx.x * 256 + threadIdx.x;
    int stride = gridDim.x * 256;

    for (int i = g; i < N64; i += stride) cnt[i] = 0;    // full padded range

    // W [K,64] -> W^T [64,K]  (output-indexed: writes coalesce)
    for (int o = g; o < 40960; o += stride) {
        if (o < 8192) {                                  // T0: [64][128] from W0 [128][64]
            int n = o >> 7, k = o & 127;
            T0[o] = f32 ? f2b(((const float*)W0)[k * 64 + n])
                        : ((const unsigned short*)W0)[k * 64 + n];    // raw bf16 copy
        } else {
            int oo = o - 8192;
            const void* W; unsigned short* T;
            if (oo < 16384) { W = W1; T = T1; }
            else            { W = W2; T = T2; oo -= 16384; }
            int n = oo >> 8, k = oo & 255;               // T: [64][256]
            float w = ldw(W, k * 64 + n, f32);
            T[oo] = (unsigned short)f2h(w);              // fp16 both worlds
        }
    }
    // folded attention consts: per layer L, 16 floats
    if (blockIdx.x == 0 && threadIdx.x < 48) {
        int L = threadIdx.x >> 4, s = threadIdx.x & 15;
        const void* W = (L == 0) ? Wl0 : ((L == 1) ? Wl1 : Wl2);
        const void* B = (L == 0) ? bl0 : ((L == 1) ? bl1 : bl2);
        float v = 0.f;
        if (s < 8)       v = ldw(W, s, f32);
        else if (s < 12) v = ldw(B, s - 8, f32);
        Wlp[L * 16 + s] = v * 1.44269504f;
    }
}

// ---------------- MFMA GEMM body: h = A @ W + b ----------------
template <int K, int AMODE>
__device__ __forceinline__ void gemm_body(const unsigned short* __restrict__ Ah,
                                          const unsigned short* __restrict__ Wt,
                                          const void* __restrict__ bq,
                                          bool f32,
                                          _Float16* __restrict__ h, int M, int blockId) {
    constexpr int KP = K + 8;
    __shared__ __align__(16) unsigned short Ws[64 * KP];
    int tid = threadIdx.x;
    #pragma unroll
    for (int it = 0; it < (64 * K) / 2048; it++) {       // coalesced 16B staging
        int i = it * 2048 + tid * 8;
        int row = i / K, col = i % K;
        *(s16x8*)&Ws[row * KP + col] = *(const s16x8*)(Wt + i);
    }
    __syncthreads();

    int lane = tid & 63, wv = tid >> 6;
    int m16 = lane & 15, quad = lane >> 4;

    int tiles = (M + 15) >> 4;
    int tile = blockId * 4 + wv;
    if (tile >= tiles) return;

    float bias[4];
    #pragma unroll
    for (int t = 0; t < 4; t++) bias[t] = ldw(bq, 16 * t + m16, f32);

    int m0 = tile << 4;
    int row = m0 + m16;
    bool rv = row < M;
    long abase = (long)row * K;
    f32x4 acc[4] = {{0.f,0.f,0.f,0.f},{0.f,0.f,0.f,0.f},{0.f,0.f,0.f,0.f},{0.f,0.f,0.f,0.f}};

    #pragma unroll
    for (int ks = 0; ks < K / 32; ks++) {
        int kb = ks * 32 + quad * 8;
        s16x8 b[4];
        #pragma unroll
        for (int t = 0; t < 4; t++)
            b[t] = *(const s16x8*)&Ws[(16 * t + m16) * KP + kb];     // LDS, 2-way max
        if (AMODE == 3) {
            const float* Af = (const float*)Ah;
            f32x4 v0 = {0.f,0.f,0.f,0.f}, v1 = {0.f,0.f,0.f,0.f};
            if (rv) {
                v0 = *(const f32x4*)(Af + abase + kb);
                v1 = *(const f32x4*)(Af + abase + kb + 4);
            }
            s16x8 ah, al;
            #pragma unroll
            for (int jj = 0; jj < 8; jj++) {
                float f = (jj < 4) ? v0[jj] : v1[jj - 4];
                unsigned short hb = f2b(f);
                ah[jj] = (short)hb;
                al[jj] = (short)f2b(f - b2f(hb));
            }
            #pragma unroll
            for (int t = 0; t < 4; t++)
                acc[t] = __builtin_amdgcn_mfma_f32_16x16x32_bf16(ah, b[t], acc[t], 0, 0, 0);
            #pragma unroll
            for (int t = 0; t < 4; t++)
                acc[t] = __builtin_amdgcn_mfma_f32_16x16x32_bf16(al, b[t], acc[t], 0, 0, 0);
        } else {
            s16x8 ah = rv ? *(const s16x8*)(Ah + abase + kb) : (s16x8){0,0,0,0,0,0,0,0};
            if (AMODE == 0) {
                #pragma unroll
                for (int t = 0; t < 4; t++)
                    acc[t] = __builtin_amdgcn_mfma_f32_16x16x32_bf16(ah, b[t], acc[t], 0, 0, 0);
            } else {
                #pragma unroll
                for (int t = 0; t < 4; t++)
                    acc[t] = __builtin_amdgcn_mfma_f32_16x16x32_f16(ah, b[t], acc[t], 0, 0, 0);
            }
        }
    }

    #pragma unroll
    for (int t = 0; t < 4; t++) {
        #pragma unroll
        for (int r = 0; r < 4; r++) {
            int orow = m0 + quad * 4 + r;        // C/D: col=lane&15, row=quad*4+reg
            if (orow < M) h[(long)orow * 64 + 16 * t + m16] = (_Float16)(acc[t][r] + bias[t]);
        }
    }
}

// layers 1-2: A = x fp16 single plane, BOTH worlds. flag only picks bias dtype.
template <int K>
__global__ __launch_bounds__(256) void gemm_mfma(const unsigned short* __restrict__ Ah,
                                                 const unsigned short* __restrict__ Wt,
                                                 const void* __restrict__ bq,
                                                 const int* __restrict__ flag,
                                                 _Float16* __restrict__ h, int M) {
    const bool f32 = (*flag >= 8);
    gemm_body<K, 1>(Ah, Wt, bq, f32, h, M, blockIdx.x);
}

// ---------------- fused: slot scatter + layer-0 GEMM (single atomic pass) --------
__global__ __launch_bounds__(256) void gemm0_scatter(
    const void* __restrict__ nodes,
    const unsigned short* __restrict__ Wt, const void* __restrict__ bq,
    const int* __restrict__ flag, _Float16* __restrict__ h, int M,
    const int* __restrict__ recv, const int* __restrict__ send,
    int* __restrict__ cnt, unsigned short* __restrict__ slots, int E, int scatBlocks) {
    if ((int)blockIdx.x < scatBlocks) {
        int g = blockIdx.x * 256 + threadIdx.x;
        int stride = scatBlocks * 256;
        for (int i = g; i < E; i += stride) {
            int r = recv[i];
            int pos = atomicAdd(&cnt[r], 1);
            if (pos < 64) slots[r * 64 + pos] = (unsigned short)send[i];
        }
    } else {
        const bool f32 = (*flag >= 8);
        int blockId = blockIdx.x - scatBlocks;
        if (f32) gemm_body<128, 3>((const unsigned short*)nodes, Wt, bq,
                                   true, h, M, blockId);
        else     gemm_body<128, 0>((const unsigned short*)nodes, Wt, bq,
                                   false, h, M, blockId);
    }
}

// ---------------- Attention: segment softmax (no-max, exp2-folded) + aggregate ----
// One wave per receiver; lane = hidden dim. R27: the xh STORE (and final out
// store) are the ONLY nt-tagged accesses -- R11 diag showed FETCH=15.6MB vs
// ~6.5MB ideal: the 12.8MB xh write stream evicts h (3.2MB/XCD-L2 of 4MB) and
// gathers fall to L3/HBM. nt = evict-first for the write stream; h stays hot.
// (R9 lesson: nt on RE-READ data -- slots, gemm A -- is poison; not repeated.)
// R12: no in-wave GEMM fusion. R15/R19: no 16x batching. R20: no 2x pairing.
// R21/R5: GEMM needs LDS-staged B. 1 receiver/wave, max TLP. VGPR=32 (R11 diag).
__global__ __launch_bounds__(256) void attn_kernel(
    const _Float16* __restrict__ h, const int* __restrict__ cnt,
    const unsigned short* __restrict__ slots,
    const float* __restrict__ wlp,          // 12 pre-folded consts (prep_kernel)
    const int* __restrict__ flag,
    unsigned short* __restrict__ xh,
    void* __restrict__ out, int n, int last) {
    const bool f32 = (*flag >= 8);
    int lane = threadIdx.x & 63;
    int r = __builtin_amdgcn_readfirstlane(blockIdx.x * 4 + (threadIdx.x >> 6));
    if (r >= n) return;

    int cR = cnt[r];
    cR = min(cR, 64);
    int sv = slots[r * 64 + lane];           // one coalesced 128B row per wave
    if (lane >= cR) sv = 0;                  // clamp: valid h row, value unused

    float hr = (float)h[(long)r * HID + lane];
    f32x4 w0v = *(const f32x4*)(wlp);        // already *log2e
    f32x4 w1v = *(const f32x4*)(wlp + 4);
    f32x4 bv  = *(const f32x4*)(wlp + 8);
    f32x2 w0p[2], cp[2];
    #pragma unroll
    for (int q = 0; q < 2; q++) {
        #pragma unroll
        for (int c = 0; c < 2; c++) {
            int k = 2 * q + c;
            w0p[q][c] = w0v[k];
            cp[q][c] = fmaf(hr, w1v[k], bv[k]);  // receiver part: loop-invariant
        }
    }
    f32x2 lp[2] = {{0.f, 0.f}, {0.f, 0.f}};
    f32x2 ap[2] = {{0.f, 0.f}, {0.f, 0.f}};
    edge_softmax(h + lane, sv, cR, w0p, cp, lp, ap);

    bool has = (cR > 0);
    if (!last) {
        float v[4];
        #pragma unroll
        for (int k = 0; k < HEADS; k++) {
            float a = has ? ap[k >> 1][k & 1] * RCP(lp[k >> 1][k & 1]) : 0.f;
            v[k] = (a > 0.f) ? a : (__expf(a) - 1.f);    // elu
        }
        long o = (long)r * (HID * HEADS) + lane * HEADS; // reshape: d*HEADS+k
        s16x4 vf;                                        // single fp16 plane
        #pragma unroll
        for (int k = 0; k < HEADS; k++) vf[k] = f2h(v[k]);
        __builtin_nontemporal_store(vf, (s16x4*)(xh + o));  // evict-first: keep h hot
    } else {
        float s = 0.f;
        #pragma unroll
        for (int k = 0; k < HEADS; k++)
            s += has ? ap[k >> 1][k & 1] * RCP(lp[k >> 1][k & 1]) : 0.f;
        float a = s * 0.25f;                             // mean over heads
        a = (a > 0.f) ? a : (__expf(a) - 1.f);           // elu
        if (f32) __builtin_nontemporal_store(a, (float*)out + (long)r * HID + lane);
        else     __builtin_nontemporal_store(f2b(a),     // bf16 bits via u16 ptr
                     (unsigned short*)out + (long)r * HID + lane);
    }
}

// ---------------- launch ----------------

extern "C" void kernel_launch(void* const* d_in, const int* in_sizes, int n_in,
                              void* d_out, int out_size, void* d_ws, size_t ws_size,
                              hipStream_t stream) {
    const void* nodes    = d_in[0];
    const int* senders   = (const int*)d_in[1];
    const int* receivers = (const int*)d_in[2];
    const void* Wq0 = d_in[3];  const void* bq0 = d_in[4];
    const void* Wl0 = d_in[5];  const void* bl0 = d_in[6];
    const void* Wq1 = d_in[7];  const void* bq1 = d_in[8];
    const void* Wl1 = d_in[9];  const void* bl1 = d_in[10];
    const void* Wq2 = d_in[11]; const void* bq2 = d_in[12];
    const void* Wl2 = d_in[13]; const void* bl2 = d_in[14];

    int N = in_sizes[0] / 128;
    int E = in_sizes[1];
    int N64 = ((N + 63) / 64) * 64;

    char* p = (char*)d_ws;
    int* flag = (int*)p;            p += 64;
    _Float16* h = (_Float16*)p;     p += (size_t)N64 * 64 * 2;          // 3.2 MB (L2-fit)
    unsigned short* xh = (unsigned short*)p;  p += (size_t)N64 * 256 * 2; // 12.8 MB fp16
    unsigned short* Wt0 = (unsigned short*)p; p += 128 * 64 * 2;
    unsigned short* Wt1 = (unsigned short*)p; p += 256 * 64 * 2;
    unsigned short* Wt2 = (unsigned short*)p; p += 256 * 64 * 2;
    float* Wlp = (float*)p;         p += 64 * 4;                        // 3x16 floats
    int* cnt = (int*)p;             p += (size_t)N64 * 4;
    unsigned short* slots = (unsigned short*)p; p += (size_t)N64 * 64 * 2; // 3.2 MB u16

    prep_kernel<<<64, 256, 0, stream>>>(nodes, Wq0, Wq1, Wq2,
                                        Wl0, bl0, Wl1, bl1, Wl2, bl2,
                                        flag, Wt0, Wt1, Wt2, Wlp, cnt, N64);

    int attnGrid = (N + 3) / 4;
    int tiles = (N + 15) / 16;
    int gemmGrid = (tiles + 3) / 4;
    int scatBlocks = gemmGrid;

    // layer-0 GEMM (direct nodes read, in-register hi/lo for f32) + slot scatter
    gemm0_scatter<<<scatBlocks + gemmGrid, 256, 0, stream>>>(nodes, Wt0, bq0, flag, h, N,
                                                             receivers, senders, cnt, slots,
                                                             E, scatBlocks);
    attn_kernel<<<attnGrid, 256, 0, stream>>>(h, cnt, slots, Wlp + 0, flag,
                                              xh, nullptr, N, 0);
    // layer 1
    gemm_mfma<256><<<gemmGrid, 256, 0, stream>>>(xh, Wt1, bq1, flag, h, N);
    attn_kernel<<<attnGrid, 256, 0, stream>>>(h, cnt, slots, Wlp + 16, flag,
                                              xh, nullptr, N, 0);
    // layer 2 (last: mean over heads + elu)
    gemm_mfma<256><<<gemmGrid, 256, 0, stream>>>(xh, Wt2, bq2, flag, h, N);
    attn_kernel<<<attnGrid, 256, 0, stream>>>(h, cnt, slots, Wlp + 32, flag,
                                              nullptr, d_out, N, 1);
}

// Round 14
// 205.133 us; speedup vs baseline: 1.1132x; 1.0160x over previous
//
#include <hip/hip_runtime.h>
#include <hip/hip_bf16.h>

#define HID 64
#define HEADS 4

typedef short s16x8 __attribute__((ext_vector_type(8)));   // 8 bf16/f16 (4 VGPRs)
typedef short s16x4 __attribute__((ext_vector_type(4)));
typedef float f32x4 __attribute__((ext_vector_type(4)));
typedef float f32x2 __attribute__((ext_vector_type(2)));

// flag convention: *flag >= 8  =>  float inputs are fp32; else bf16.
__device__ __forceinline__ float ldw(const void* p, long i, bool f32) {
    return f32 ? ((const float*)p)[i] : (float)((const __hip_bfloat16*)p)[i];
}

__device__ __forceinline__ unsigned short f2b(float f) {   // fp32 -> bf16 bits (RNE, finite)
    unsigned int u = __builtin_bit_cast(unsigned int, f);
    u += 0x7FFF + ((u >> 16) & 1);
    return (unsigned short)(u >> 16);
}
__device__ __forceinline__ float b2f(unsigned short s) {
    unsigned int u = ((unsigned int)s) << 16;
    return __builtin_bit_cast(float, u);
}
__device__ __forceinline__ short f2h(float f) {            // fp32 -> fp16 bits
    return __builtin_bit_cast(short, (_Float16)f);
}

#if __has_builtin(__builtin_amdgcn_exp2f)
#define EXP2(x) __builtin_amdgcn_exp2f(x)     // single v_exp_f32
#else
#define EXP2(x) exp2f(x)
#endif
#if __has_builtin(__builtin_amdgcn_rcpf)
#define RCP(x) __builtin_amdgcn_rcpf(x)
#else
#define RCP(x) (1.0f / (x))
#endif

// ---------------- shared edge-softmax core: depth-16 raw-load pipeline (R25) -----
// sv holds UNSCALED u16 sender ids; index = readlane(sv,j)*HID (scalar shift).
// lanes with lane >= cR must arrive with sv == 0 (safe gather of h row 0).
// Two 8-deep banks q/p: all 16 loads in flight at wave start for deg<=16.
// SESSION LESSONS (final state): depth-16 +1us (R25); nt loads poison re-read
// data (R9, -6us); nt stores neutral (R27); 16x receiver batching kills TLP
// (R2/R19, -55%); 2x interleaved pairing doubles reg state (R20, -4%);
// LDS-free GEMM is latency-poison (R21, -29us). Remaining cost = 7-dispatch
// serial chain x per-boundary L2 invalidation + harness L3 poison (R11 diag:
// ~15us fixed/pass) -- structural, needs single-dispatch producer-consumer
// fusion which G16 (dispatch-order correctness) forbids.
__device__ __forceinline__ void edge_softmax(
    const _Float16* __restrict__ hbp, int sv, int cR,
    const f32x2 (&w0p)[2], const f32x2 (&cp)[2],
    f32x2 (&lp)[2], f32x2 (&ap)[2]) {
    #define LD(j) hbp[(long)(__builtin_amdgcn_readlane(sv, (j)) * HID)]
    #define STEP(hc) {                                                     \
        float _h = (float)(hc);              /* cvt at USE time */         \
        _Pragma("unroll")                                                  \
        for (int q = 0; q < 2; q++) {                                      \
            f32x2 t = w0p[q] * _h + cp[q];                                 \
            f32x2 u = t * 0.2f;                                            \
            t.x = fmaxf(t.x, u.x); t.y = fmaxf(t.y, u.y);                  \
            f32x2 pe; pe.x = EXP2(t.x); pe.y = EXP2(t.y);                  \
            lp[q] += pe;                                                   \
            ap[q] += pe * _h;                                              \
        } }

    _Float16 q0 = LD(0), q1 = LD(1), q2 = LD(2), q3 = LD(3);   // bank q: [j, j+8)
    _Float16 q4 = LD(4), q5 = LD(5), q6 = LD(6), q7 = LD(7);
    _Float16 p0 = LD(8), p1 = LD(9), p2 = LD(10), p3 = LD(11); // bank p: [j+8, j+16)
    _Float16 p4 = LD(12), p5 = LD(13), p6 = LD(14), p7 = LD(15);
    int j = 0;
    for (; j + 8 <= cR; j += 8) {
        _Float16 a0 = q0, a1 = q1, a2 = q2, a3 = q3;
        _Float16 a4 = q4, a5 = q5, a6 = q6, a7 = q7;
        q0 = p0; q1 = p1; q2 = p2; q3 = p3;          // shift p -> q
        q4 = p4; q5 = p5; q6 = p6; q7 = p7;
        if (j + 16 < cR) {                           // refill p 16 ahead (guarded)
            p0 = LD(j + 16); p1 = LD(j + 17); p2 = LD(j + 18); p3 = LD(j + 19);
            p4 = LD(j + 20); p5 = LD(j + 21); p6 = LD(j + 22); p7 = LD(j + 23);
        }
        STEP(a0); STEP(a1); STEP(a2); STEP(a3);
        STEP(a4); STEP(a5); STEP(a6); STEP(a7);
    }
    int remn = cR - j;                       // 0..7 tail, bank q already loaded
    if (remn > 0) STEP(q0);
    if (remn > 1) STEP(q1);
    if (remn > 2) STEP(q2);
    if (remn > 3) STEP(q3);
    if (remn > 4) STEP(q4);
    if (remn > 5) STEP(q5);
    if (remn > 6) STEP(q6);
    #undef LD
    #undef STEP
}

// ---------------- prep: SELF-DETECT + W^T + folded attn consts + cnt zero -------
__global__ __launch_bounds__(256) void prep_kernel(
    const void* __restrict__ nodes,
    const void* __restrict__ W0, const void* __restrict__ W1, const void* __restrict__ W2,
    const void* __restrict__ Wl0, const void* __restrict__ bl0,
    const void* __restrict__ Wl1, const void* __restrict__ bl1,
    const void* __restrict__ Wl2, const void* __restrict__ bl2,
    int* __restrict__ flag_out,
    unsigned short* __restrict__ T0, unsigned short* __restrict__ T1,
    unsigned short* __restrict__ T2, float* __restrict__ Wlp,
    int* __restrict__ cnt, int N64) {
    __shared__ int sflag;
    if (threadIdx.x == 0) sflag = 0;
    __syncthreads();
    {
        const uint4* pw = (const uint4*)nodes;       // 2048 uint4 = 16384 ushorts
        int hits = 0;
        for (int i = threadIdx.x; i < 2048; i += 256) {
            uint4 u = pw[i];
            unsigned int w[4] = {u.x, u.y, u.z, u.w};
            #pragma unroll
            for (int j = 0; j < 4; j++) {
                if ((w[j] & 0x7F80u) == 0x7F80u) hits++;               // low half
                if (((w[j] >> 16) & 0x7F80u) == 0x7F80u) hits++;       // high half
            }
        }
        if (__ballot(hits != 0)) { if ((threadIdx.x & 63) == 0) sflag = 1; }
    }
    __syncthreads();
    const bool f32 = (sflag != 0);
    if (blockIdx.x == 0 && threadIdx.x == 0) *flag_out = f32 ? 100 : 0;

    int g = blockIdx.x * 256 + threadIdx.x;
    int stride = gridDim.x * 256;

    for (int i = g; i < N64; i += stride) cnt[i] = 0;    // full padded range

    // W [K,64] -> W^T [64,K]  (output-indexed: writes coalesce)
    for (int o = g; o < 40960; o += stride) {
        if (o < 8192) {                                  // T0: [64][128] from W0 [128][64]
            int n = o >> 7, k = o & 127;
            T0[o] = f32 ? f2b(((const float*)W0)[k * 64 + n])
                        : ((const unsigned short*)W0)[k * 64 + n];    // raw bf16 copy
        } else {
            int oo = o - 8192;
            const void* W; unsigned short* T;
            if (oo < 16384) { W = W1; T = T1; }
            else            { W = W2; T = T2; oo -= 16384; }
            int n = oo >> 8, k = oo & 255;               // T: [64][256]
            float w = ldw(W, k * 64 + n, f32);
            T[oo] = (unsigned short)f2h(w);              // fp16 both worlds
        }
    }
    // folded attention consts: per layer L, 16 floats
    if (blockIdx.x == 0 && threadIdx.x < 48) {
        int L = threadIdx.x >> 4, s = threadIdx.x & 15;
        const void* W = (L == 0) ? Wl0 : ((L == 1) ? Wl1 : Wl2);
        const void* B = (L == 0) ? bl0 : ((L == 1) ? bl1 : bl2);
        float v = 0.f;
        if (s < 8)       v = ldw(W, s, f32);
        else if (s < 12) v = ldw(B, s - 8, f32);
        Wlp[L * 16 + s] = v * 1.44269504f;
    }
}

// ---------------- MFMA GEMM body: h = A @ W + b ----------------
template <int K, int AMODE>
__device__ __forceinline__ void gemm_body(const unsigned short* __restrict__ Ah,
                                          const unsigned short* __restrict__ Wt,
                                          const void* __restrict__ bq,
                                          bool f32,
                                          _Float16* __restrict__ h, int M, int blockId) {
    constexpr int KP = K + 8;
    __shared__ __align__(16) unsigned short Ws[64 * KP];
    int tid = threadIdx.x;
    #pragma unroll
    for (int it = 0; it < (64 * K) / 2048; it++) {       // coalesced 16B staging
        int i = it * 2048 + tid * 8;
        int row = i / K, col = i % K;
        *(s16x8*)&Ws[row * KP + col] = *(const s16x8*)(Wt + i);
    }
    __syncthreads();

    int lane = tid & 63, wv = tid >> 6;
    int m16 = lane & 15, quad = lane >> 4;

    int tiles = (M + 15) >> 4;
    int tile = blockId * 4 + wv;
    if (tile >= tiles) return;

    float bias[4];
    #pragma unroll
    for (int t = 0; t < 4; t++) bias[t] = ldw(bq, 16 * t + m16, f32);

    int m0 = tile << 4;
    int row = m0 + m16;
    bool rv = row < M;
    long abase = (long)row * K;
    f32x4 acc[4] = {{0.f,0.f,0.f,0.f},{0.f,0.f,0.f,0.f},{0.f,0.f,0.f,0.f},{0.f,0.f,0.f,0.f}};

    #pragma unroll
    for (int ks = 0; ks < K / 32; ks++) {
        int kb = ks * 32 + quad * 8;
        s16x8 b[4];
        #pragma unroll
        for (int t = 0; t < 4; t++)
            b[t] = *(const s16x8*)&Ws[(16 * t + m16) * KP + kb];     // LDS, 2-way max
        if (AMODE == 3) {
            const float* Af = (const float*)Ah;
            f32x4 v0 = {0.f,0.f,0.f,0.f}, v1 = {0.f,0.f,0.f,0.f};
            if (rv) {
                v0 = *(const f32x4*)(Af + abase + kb);
                v1 = *(const f32x4*)(Af + abase + kb + 4);
            }
            s16x8 ah, al;
            #pragma unroll
            for (int jj = 0; jj < 8; jj++) {
                float f = (jj < 4) ? v0[jj] : v1[jj - 4];
                unsigned short hb = f2b(f);
                ah[jj] = (short)hb;
                al[jj] = (short)f2b(f - b2f(hb));
            }
            #pragma unroll
            for (int t = 0; t < 4; t++)
                acc[t] = __builtin_amdgcn_mfma_f32_16x16x32_bf16(ah, b[t], acc[t], 0, 0, 0);
            #pragma unroll
            for (int t = 0; t < 4; t++)
                acc[t] = __builtin_amdgcn_mfma_f32_16x16x32_bf16(al, b[t], acc[t], 0, 0, 0);
        } else {
            s16x8 ah = rv ? *(const s16x8*)(Ah + abase + kb) : (s16x8){0,0,0,0,0,0,0,0};
            if (AMODE == 0) {
                #pragma unroll
                for (int t = 0; t < 4; t++)
                    acc[t] = __builtin_amdgcn_mfma_f32_16x16x32_bf16(ah, b[t], acc[t], 0, 0, 0);
            } else {
                #pragma unroll
                for (int t = 0; t < 4; t++)
                    acc[t] = __builtin_amdgcn_mfma_f32_16x16x32_f16(ah, b[t], acc[t], 0, 0, 0);
            }
        }
    }

    #pragma unroll
    for (int t = 0; t < 4; t++) {
        #pragma unroll
        for (int r = 0; r < 4; r++) {
            int orow = m0 + quad * 4 + r;        // C/D: col=lane&15, row=quad*4+reg
            if (orow < M) h[(long)orow * 64 + 16 * t + m16] = (_Float16)(acc[t][r] + bias[t]);
        }
    }
}

// layers 1-2: A = x fp16 single plane, BOTH worlds. flag only picks bias dtype.
template <int K>
__global__ __launch_bounds__(256) void gemm_mfma(const unsigned short* __restrict__ Ah,
                                                 const unsigned short* __restrict__ Wt,
                                                 const void* __restrict__ bq,
                                                 const int* __restrict__ flag,
                                                 _Float16* __restrict__ h, int M) {
    const bool f32 = (*flag >= 8);
    gemm_body<K, 1>(Ah, Wt, bq, f32, h, M, blockIdx.x);
}

// ---------------- fused: slot scatter + layer-0 GEMM (single atomic pass) --------
__global__ __launch_bounds__(256) void gemm0_scatter(
    const void* __restrict__ nodes,
    const unsigned short* __restrict__ Wt, const void* __restrict__ bq,
    const int* __restrict__ flag, _Float16* __restrict__ h, int M,
    const int* __restrict__ recv, const int* __restrict__ send,
    int* __restrict__ cnt, unsigned short* __restrict__ slots, int E, int scatBlocks) {
    if ((int)blockIdx.x < scatBlocks) {
        int g = blockIdx.x * 256 + threadIdx.x;
        int stride = scatBlocks * 256;
        for (int i = g; i < E; i += stride) {
            int r = recv[i];
            int pos = atomicAdd(&cnt[r], 1);
            if (pos < 64) slots[r * 64 + pos] = (unsigned short)send[i];
        }
    } else {
        const bool f32 = (*flag >= 8);
        int blockId = blockIdx.x - scatBlocks;
        if (f32) gemm_body<128, 3>((const unsigned short*)nodes, Wt, bq,
                                   true, h, M, blockId);
        else     gemm_body<128, 0>((const unsigned short*)nodes, Wt, bq,
                                   false, h, M, blockId);
    }
}

// ---------------- Attention: segment softmax (no-max, exp2-folded) + aggregate ----
// One wave per receiver; lane = hidden dim. fp16 h rows. Depth-16 gather
// pipeline (R25), plain loads/stores. Slot table: single <=64 chunk, lanes
// >= cnt clamped to slot 0. 1 receiver/wave, max TLP. VGPR=32 (R11 diag).
__global__ __launch_bounds__(256) void attn_kernel(
    const _Float16* __restrict__ h, const int* __restrict__ cnt,
    const unsigned short* __restrict__ slots,
    const float* __restrict__ wlp,          // 12 pre-folded consts (prep_kernel)
    const int* __restrict__ flag,
    unsigned short* __restrict__ xh,
    void* __restrict__ out, int n, int last) {
    const bool f32 = (*flag >= 8);
    int lane = threadIdx.x & 63;
    int r = __builtin_amdgcn_readfirstlane(blockIdx.x * 4 + (threadIdx.x >> 6));
    if (r >= n) return;

    int cR = cnt[r];
    cR = min(cR, 64);
    int sv = slots[r * 64 + lane];           // one coalesced 128B row per wave
    if (lane >= cR) sv = 0;                  // clamp: valid h row, value unused

    float hr = (float)h[(long)r * HID + lane];
    f32x4 w0v = *(const f32x4*)(wlp);        // already *log2e
    f32x4 w1v = *(const f32x4*)(wlp + 4);
    f32x4 bv  = *(const f32x4*)(wlp + 8);
    f32x2 w0p[2], cp[2];
    #pragma unroll
    for (int q = 0; q < 2; q++) {
        #pragma unroll
        for (int c = 0; c < 2; c++) {
            int k = 2 * q + c;
            w0p[q][c] = w0v[k];
            cp[q][c] = fmaf(hr, w1v[k], bv[k]);  // receiver part: loop-invariant
        }
    }
    f32x2 lp[2] = {{0.f, 0.f}, {0.f, 0.f}};
    f32x2 ap[2] = {{0.f, 0.f}, {0.f, 0.f}};
    edge_softmax(h + lane, sv, cR, w0p, cp, lp, ap);

    bool has = (cR > 0);
    if (!last) {
        float v[4];
        #pragma unroll
        for (int k = 0; k < HEADS; k++) {
            float a = has ? ap[k >> 1][k & 1] * RCP(lp[k >> 1][k & 1]) : 0.f;
            v[k] = (a > 0.f) ? a : (__expf(a) - 1.f);    // elu
        }
        long o = (long)r * (HID * HEADS) + lane * HEADS; // reshape: d*HEADS+k
        s16x4 vf;                                        // single fp16 plane
        #pragma unroll
        for (int k = 0; k < HEADS; k++) vf[k] = f2h(v[k]);
        *(s16x4*)(xh + o) = vf;
    } else {
        float s = 0.f;
        #pragma unroll
        for (int k = 0; k < HEADS; k++)
            s += has ? ap[k >> 1][k & 1] * RCP(lp[k >> 1][k & 1]) : 0.f;
        float a = s * 0.25f;                             // mean over heads
        a = (a > 0.f) ? a : (__expf(a) - 1.f);           // elu
        if (f32) ((float*)out)[(long)r * HID + lane] = a;
        else     ((__hip_bfloat16*)out)[(long)r * HID + lane] = (__hip_bfloat16)a;
    }
}

// ---------------- launch ----------------

extern "C" void kernel_launch(void* const* d_in, const int* in_sizes, int n_in,
                              void* d_out, int out_size, void* d_ws, size_t ws_size,
                              hipStream_t stream) {
    const void* nodes    = d_in[0];
    const int* senders   = (const int*)d_in[1];
    const int* receivers = (const int*)d_in[2];
    const void* Wq0 = d_in[3];  const void* bq0 = d_in[4];
    const void* Wl0 = d_in[5];  const void* bl0 = d_in[6];
    const void* Wq1 = d_in[7];  const void* bq1 = d_in[8];
    const void* Wl1 = d_in[9];  const void* bl1 = d_in[10];
    const void* Wq2 = d_in[11]; const void* bq2 = d_in[12];
    const void* Wl2 = d_in[13]; const void* bl2 = d_in[14];

    int N = in_sizes[0] / 128;
    int E = in_sizes[1];
    int N64 = ((N + 63) / 64) * 64;

    char* p = (char*)d_ws;
    int* flag = (int*)p;            p += 64;
    _Float16* h = (_Float16*)p;     p += (size_t)N64 * 64 * 2;          // 3.2 MB (L2-fit)
    unsigned short* xh = (unsigned short*)p;  p += (size_t)N64 * 256 * 2; // 12.8 MB fp16
    unsigned short* Wt0 = (unsigned short*)p; p += 128 * 64 * 2;
    unsigned short* Wt1 = (unsigned short*)p; p += 256 * 64 * 2;
    unsigned short* Wt2 = (unsigned short*)p; p += 256 * 64 * 2;
    float* Wlp = (float*)p;         p += 64 * 4;                        // 3x16 floats
    int* cnt = (int*)p;             p += (size_t)N64 * 4;
    unsigned short* slots = (unsigned short*)p; p += (size_t)N64 * 64 * 2; // 3.2 MB u16

    prep_kernel<<<64, 256, 0, stream>>>(nodes, Wq0, Wq1, Wq2,
                                        Wl0, bl0, Wl1, bl1, Wl2, bl2,
                                        flag, Wt0, Wt1, Wt2, Wlp, cnt, N64);

    int attnGrid = (N + 3) / 4;
    int tiles = (N + 15) / 16;
    int gemmGrid = (tiles + 3) / 4;
    int scatBlocks = gemmGrid;

    // layer-0 GEMM (direct nodes read, in-register hi/lo for f32) + slot scatter
    gemm0_scatter<<<scatBlocks + gemmGrid, 256, 0, stream>>>(nodes, Wt0, bq0, flag, h, N,
                                                             receivers, senders, cnt, slots,
                                                             E, scatBlocks);
    attn_kernel<<<attnGrid, 256, 0, stream>>>(h, cnt, slots, Wlp + 0, flag,
                                              xh, nullptr, N, 0);
    // layer 1
    gemm_mfma<256><<<gemmGrid, 256, 0, stream>>>(xh, Wt1, bq1, flag, h, N);
    attn_kernel<<<attnGrid, 256, 0, stream>>>(h, cnt, slots, Wlp + 16, flag,
                                              xh, nullptr, N, 0);
    // layer 2 (last: mean over heads + elu)
    gemm_mfma<256><<<gemmGrid, 256, 0, stream>>>(xh, Wt2, bq2, flag, h, N);
    attn_kernel<<<attnGrid, 256, 0, stream>>>(h, cnt, slots, Wlp + 32, flag,
                                              nullptr, d_out, N, 1);
}